// Round 5
// baseline (225.426 us; speedup 1.0000x reference)
//
#include <hip/hip_runtime.h>

#define NN 50000
#define NE 1600000
#define NG 512
#define NXCD 8
#define RSPAN 6250                         // NN / NXCD rows per bucket
#define CAP 96                             // padded CSR row capacity (mean deg 32, 11 sigma)
#define BCAP 262144                        // bucket capacity (mean 200K, sd ~420)
#define PB_BLOCKS 512
#define PB_EPB (NE / PB_BLOCKS)            // 3125 edges per partition block
#define G1_BLOCKS ((NN * 32) / 256)        // 6250 (exact)
#define FILL_BLOCKS 1024                   // multiple of 8
#define BPG (FILL_BLOCKS / NXCD)           // 128 blocks per group

// ---------- fused: single-pass edge radix-partition (8 buckets)  +  layer-1 GEMM ----------
// blocks [0, PB_BLOCKS): read edge chunk once, bucket by row/RSPAN, append packed
//   ((row-rlo)<<16)|col records contiguously (block-reserved ranges -> coalesced).
// blocks [PB_BLOCKS, +G1_BLOCKS): y[n][0:16]=x[n]@c1_fc^T, [16:32]=x[n]@c1e_fc^T
//   with W transposed in LDS (Wt[k][o]: lane o -> bank o, conflict-free).
__global__ __launch_bounds__(256) void part_gemm1(const int* __restrict__ ei,
                                                  int* __restrict__ bcur,
                                                  unsigned int* __restrict__ bucket,
                                                  const float* __restrict__ x,
                                                  const float* __restrict__ w_a,
                                                  const float* __restrict__ w_b,
                                                  float* __restrict__ y) {
    int tid = threadIdx.x;
    if (blockIdx.x < PB_BLOCKS) {
        __shared__ int lcnt[8];
        __shared__ int lcur[8];
        if (tid < 8) lcnt[tid] = 0;
        __syncthreads();
        int e0 = blockIdx.x * PB_EPB, e1 = e0 + PB_EPB;  // NE divisible by PB_BLOCKS
        for (int e = e0 + tid; e < e1; e += 256) {
            int g = ei[e] / RSPAN;
            atomicAdd(&lcnt[g], 1);
        }
        __syncthreads();
        if (tid < 8) lcur[tid] = atomicAdd(&bcur[tid], lcnt[tid]);
        __syncthreads();
        for (int e = e0 + tid; e < e1; e += 256) {
            int row = ei[e], col = ei[NE + e];
            int g = row / RSPAN;
            int pos = atomicAdd(&lcur[g], 1);
            if (pos < BCAP)
                bucket[g * BCAP + pos] = ((unsigned)(row - g * RSPAN) << 16) | (unsigned)col;
        }
    } else {
        __shared__ float Wt[64][32];  // Wt[k][o]
        for (int i = tid; i < 16 * 64; i += 256) {
            Wt[i & 63][i >> 6] = w_a[i];          // o = i>>6 in [0,16)
            Wt[i & 63][16 + (i >> 6)] = w_b[i];   // o in [16,32)
        }
        __syncthreads();
        int idx = (blockIdx.x - PB_BLOCKS) * 256 + tid;
        int n = idx >> 5, o = idx & 31;
        const float4* xr = reinterpret_cast<const float4*>(x + n * 64);
        float acc = 0.f;
#pragma unroll
        for (int k4 = 0; k4 < 16; ++k4) {
            float4 a = xr[k4];
            acc += a.x * Wt[4 * k4 + 0][o] + a.y * Wt[4 * k4 + 1][o] +
                   a.z * Wt[4 * k4 + 2][o] + a.w * Wt[4 * k4 + 3][o];
        }
        y[idx] = acc;
    }
}

// ---------- padded-CSR fill from buckets: all traffic XCD-local ----------
__global__ __launch_bounds__(256) void fill2(const int* __restrict__ bcur,
                                             const unsigned int* __restrict__ bucket,
                                             int* __restrict__ cursor,
                                             unsigned short* __restrict__ cols) {
    int grp = blockIdx.x & 7;
    int j = blockIdx.x >> 3;
    int cnt = min(bcur[grp], BCAP);
    int per = (cnt + BPG - 1) / BPG;
    int e0 = j * per, e1 = min(e0 + per, cnt);
    int rlo = grp * RSPAN;
    const unsigned int* b = bucket + grp * BCAP;
    for (int e = e0 + threadIdx.x; e < e1; e += 256) {
        unsigned int v = b[e];
        int row = rlo + (int)(v >> 16);
        int pos = atomicAdd(&cursor[row], 1);
        if (pos < CAP) cols[row * CAP + pos] = (unsigned short)(v & 0xffffu);
    }
}

// ---------- layer-1 gather: h[n] = relu(sum_e y[cols[e]]), 8 threads/node ----------
__global__ __launch_bounds__(256) void gather32relu(const int* __restrict__ cursor,
                                                    const unsigned short* __restrict__ cols,
                                                    const float* __restrict__ src,
                                                    float* __restrict__ out) {
    int idx = blockIdx.x * 256 + threadIdx.x;
    if (idx >= NN * 8) return;
    int n = idx >> 3, g = idx & 7;
    int deg = min(cursor[n], CAP);
    const unsigned short* c = cols + n * CAP;
    const float4* y4 = reinterpret_cast<const float4*>(src);
    float4 acc = {0.f, 0.f, 0.f, 0.f};
    int i = 0;
    for (; i + 1 < deg; i += 2) {
        float4 a = y4[(int)c[i] * 8 + g];
        float4 b = y4[(int)c[i + 1] * 8 + g];
        acc.x += a.x + b.x;
        acc.y += a.y + b.y;
        acc.z += a.z + b.z;
        acc.w += a.w + b.w;
    }
    if (i < deg) {
        float4 a = y4[(int)c[i] * 8 + g];
        acc.x += a.x; acc.y += a.y; acc.z += a.z; acc.w += a.w;
    }
    acc.x = fmaxf(acc.x, 0.f);
    acc.y = fmaxf(acc.y, 0.f);
    acc.z = fmaxf(acc.z, 0.f);
    acc.w = fmaxf(acc.w, 0.f);
    reinterpret_cast<float4*>(out)[n * 8 + g] = acc;
}

// ---------- fused layer-2: gather-sum + (u @ W2 -> relu) via LDS ----------
__global__ __launch_bounds__(256) void gather_gemm2(const int* __restrict__ cursor,
                                                    const unsigned short* __restrict__ cols,
                                                    const float* __restrict__ h,
                                                    const float* __restrict__ w_a,
                                                    const float* __restrict__ w_b,
                                                    float* __restrict__ rt) {
    __shared__ float U[32][33];
    __shared__ float W[64][17];
    int tid = threadIdx.x;
    for (int i = tid; i < 32 * 16; i += 256) W[i >> 4][i & 15] = w_a[i];
    for (int i = tid; i < 32 * 16; i += 256) W[32 + (i >> 4)][i & 15] = w_b[i];
    int nl = tid >> 3, g = tid & 7;
    int n = blockIdx.x * 32 + nl;
    float4 acc = {0.f, 0.f, 0.f, 0.f};
    if (n < NN) {
        int deg = min(cursor[n], CAP);
        const unsigned short* c = cols + n * CAP;
        const float4* h4 = reinterpret_cast<const float4*>(h);
        int i = 0;
        for (; i + 1 < deg; i += 2) {
            float4 a = h4[(int)c[i] * 8 + g];
            float4 b = h4[(int)c[i + 1] * 8 + g];
            acc.x += a.x + b.x;
            acc.y += a.y + b.y;
            acc.z += a.z + b.z;
            acc.w += a.w + b.w;
        }
        if (i < deg) {
            float4 a = h4[(int)c[i] * 8 + g];
            acc.x += a.x; acc.y += a.y; acc.z += a.z; acc.w += a.w;
        }
    }
    U[nl][g * 4 + 0] = acc.x;
    U[nl][g * 4 + 1] = acc.y;
    U[nl][g * 4 + 2] = acc.z;
    U[nl][g * 4 + 3] = acc.w;
    __syncthreads();
    int obase = g * 8;
    int ub = (g < 4) ? 0 : 16;
    float out[8];
#pragma unroll
    for (int oo = 0; oo < 8; ++oo) {
        int o = obase + oo;
        float a = 0.f;
#pragma unroll
        for (int k = 0; k < 16; ++k) a += U[nl][ub + k] * W[o][k];
        out[oo] = fmaxf(a, 0.f);
    }
    if (n < NN) {
        float4* rt4 = reinterpret_cast<float4*>(rt + n * 64 + obase);
        rt4[0] = {out[0], out[1], out[2], out[3]};
        rt4[1] = {out[4], out[5], out[6], out[7]};
    }
}

// ---------- per-graph mean pool + MLP ----------
__global__ __launch_bounds__(128) void pool_mlp(const float* __restrict__ rt,
                                                const int* __restrict__ batch,
                                                const float* __restrict__ fc1_w,
                                                const float* __restrict__ fc1_b,
                                                const float* __restrict__ fc2_w,
                                                const float* __restrict__ fc2_b,
                                                float* __restrict__ out) {
    int b = blockIdx.x;
    int tid = threadIdx.x;
    int lo = 0, hi = NN;
    while (lo < hi) { int mid = (lo + hi) >> 1; if (batch[mid] < b) lo = mid + 1; else hi = mid; }
    int start = lo;
    lo = start; hi = NN;
    while (lo < hi) { int mid = (lo + hi) >> 1; if (batch[mid] < b + 1) lo = mid + 1; else hi = mid; }
    int end = lo;

    int f = tid & 63, half = tid >> 6;
    float acc = 0.f;
    for (int n = start + half; n < end; n += 2)
        acc += rt[n * 64 + f];
    __shared__ float part[128];
    __shared__ float gvec[64];
    part[tid] = acc;
    __syncthreads();
    float cnt = (float)((end - start) > 1 ? (end - start) : 1);
    if (tid < 64) gvec[tid] = (part[tid] + part[64 + tid]) / cnt;
    __syncthreads();

    float hj = fc1_b[tid];
    const float* w = fc1_w + tid * 64;
#pragma unroll
    for (int k = 0; k < 64; ++k) hj += gvec[k] * w[k];
    hj = fmaxf(hj, 0.f);
    __shared__ float red[128];
    red[tid] = hj * fc2_w[tid];
    __syncthreads();
    for (int sft = 64; sft > 0; sft >>= 1) {
        if (tid < sft) red[tid] += red[tid + sft];
        __syncthreads();
    }
    if (tid == 0) out[b] = red[0] + fc2_b[0];
}

extern "C" void kernel_launch(void* const* d_in, const int* in_sizes, int n_in,
                              void* d_out, int out_size, void* d_ws, size_t ws_size,
                              hipStream_t stream) {
    const float* x      = (const float*)d_in[0];
    const int*   ei     = (const int*)d_in[1];
    const int*   batch  = (const int*)d_in[3];
    const float* c1_fc  = (const float*)d_in[4];
    const float* c2_fc  = (const float*)d_in[7];
    const float* c1e_fc = (const float*)d_in[10];
    const float* c2e_fc = (const float*)d_in[13];
    const float* fc1_w  = (const float*)d_in[16];
    const float* fc1_b  = (const float*)d_in[17];
    const float* fc2_w  = (const float*)d_in[18];
    const float* fc2_b  = (const float*)d_in[19];
    float* out = (float*)d_out;

    char* p = (char*)d_ws;
    int* cursor          = (int*)p;            p += sizeof(int) * NN;
    int* bcur            = (int*)p;            p += sizeof(int) * 8;
    unsigned int* bucket = (unsigned int*)p;   p += sizeof(unsigned int) * 8 * BCAP;
    unsigned short* cols = (unsigned short*)p; p += sizeof(unsigned short) * NN * CAP;
    float* y             = (float*)p;          p += sizeof(float) * NN * 32;
    float* h             = (float*)p;          p += sizeof(float) * NN * 32;
    float* rt            = (float*)p;          p += sizeof(float) * NN * 64;

    hipMemsetAsync(cursor, 0, sizeof(int) * (NN + 8), stream);  // cursor + bcur

    part_gemm1<<<PB_BLOCKS + G1_BLOCKS, 256, 0, stream>>>(ei, bcur, bucket, x, c1_fc, c1e_fc, y);
    fill2<<<FILL_BLOCKS, 256, 0, stream>>>(bcur, bucket, cursor, cols);
    gather32relu<<<(NN * 8 + 255) / 256, 256, 0, stream>>>(cursor, cols, y, h);
    gather_gemm2<<<(NN + 31) / 32, 256, 0, stream>>>(cursor, cols, h, c2_fc, c2e_fc, rt);
    pool_mlp<<<NG, 128, 0, stream>>>(rt, batch, fc1_w, fc1_b, fc2_w, fc2_b, out);
}